// Round 16
// baseline (104.534 us; speedup 1.0000x reference)
//
#include <hip/hip_runtime.h>
#include <hip/hip_bf16.h>
#include <stdint.h>

#define NE 1024
#define NH 16
#define HD 64
#define BB 2
#define TT 2048
#define MM (BB*TT)

typedef __attribute__((ext_vector_type(8))) short short8;
typedef __attribute__((ext_vector_type(4))) float floatx4;

__device__ __forceinline__ short f2bf(float f) {
    union { float f; uint32_t u; } v; v.f = f;
    uint32_t u = v.u;
    return (short)((u + 0x7fffu + ((u >> 16) & 1u)) >> 16);
}

__device__ __forceinline__ float fast_exp2(float x) {
#if __has_builtin(__builtin_amdgcn_exp2f)
    return __builtin_amdgcn_exp2f(x);
#else
    float r; asm("v_exp_f32 %0, %1" : "=v"(r) : "v"(x)); return r;
#endif
}

__device__ __forceinline__ void gload_lds16(const void* g, void* l) {
    __builtin_amdgcn_global_load_lds((__attribute__((address_space(1))) void*)g,
                                     (__attribute__((address_space(3))) void*)l,
                                     16, 0, 0);
}

// ---- fp32 -> bf16 for both inputs in one launch ----
__global__ void cvt_bf16_2(const float* __restrict__ ina, const float* __restrict__ inb,
                           short* __restrict__ outa, short* __restrict__ outb, int n8half) {
    int i = blockIdx.x * blockDim.x + threadIdx.x;
    const float* in; short* out; int j;
    if (i < n8half) { in = ina; out = outa; j = i; }
    else            { in = inb; out = outb; j = i - n8half; }
    const floatx4* p = (const floatx4*)(in + (size_t)j * 8);
    floatx4 a = p[0], b = p[1];
    union { uint32_t u[4]; short8 s; } r;
    asm("v_cvt_pk_bf16_f32 %0, %1, %2" : "=v"(r.u[0]) : "v"(a[0]), "v"(a[1]));
    asm("v_cvt_pk_bf16_f32 %0, %1, %2" : "=v"(r.u[1]) : "v"(a[2]), "v"(a[3]));
    asm("v_cvt_pk_bf16_f32 %0, %1, %2" : "=v"(r.u[2]) : "v"(b[0]), "v"(b[1]));
    asm("v_cvt_pk_bf16_f32 %0, %1, %2" : "=v"(r.u[3]) : "v"(b[2]), "v"(b[3]));
    *(short8*)(out + (size_t)j * 8) = r.s;
}

// ---- W [K,N] fp32 -> Wt [N,K] bf16 (transpose + convert; q pre-scaled) ----
__global__ void wtrans(const float* __restrict__ Wq, const float* __restrict__ Wk,
                       const float* __restrict__ Wv, short* __restrict__ Wt) {
    __shared__ float t[32][33];
    const float* W = blockIdx.z == 0 ? Wq : (blockIdx.z == 1 ? Wk : Wv);
    const float sc = (blockIdx.z == 0) ? 0.04508422f : 1.0f;  // (1/32)*log2(e)
    short* dst = Wt + (size_t)blockIdx.z * NE * NE;
    int n0 = blockIdx.x * 32, k0 = blockIdx.y * 32;
    int tx = threadIdx.x & 31, ty = threadIdx.x >> 5;
    #pragma unroll
    for (int i = 0; i < 4; i++)
        t[ty * 4 + i][tx] = W[(size_t)(k0 + ty * 4 + i) * NE + n0 + tx];
    __syncthreads();
    #pragma unroll
    for (int i = 0; i < 4; i++)
        dst[(size_t)(n0 + ty * 4 + i) * NE + k0 + tx] = f2bf(t[tx][ty * 4 + i] * sc);
}

// ---- GEMM (R6 structure): C[M,N] bf16 = A[M,K] @ Bt[N,K]^T ; 128x128 tile,
//      4 waves (2x2, acc 4x4), BK=32, 3-buf counted-vmcnt pipeline, XCD swizzle. ----
__global__ void __launch_bounds__(256) gemm_bt(const short* __restrict__ x_bf,
                                               const short* __restrict__ xenc_bf,
                                               const short* __restrict__ Wt,
                                               short* __restrict__ qkv) {
    __shared__ short sA[3][4096];
    __shared__ short sB[3][4096];
    const int bid = blockIdx.x;
    const int xcd = bid & 7, inner = bid >> 3;   // bid = xcd + 8*(x + 8*(yh + 4*z))
    const int xblk = inner & 7;
    const int yh = (inner >> 3) & 3;
    const int z = inner >> 5;
    const int yblk = xcd + 8 * yh;

    const short* A  = (z == 0) ? x_bf : xenc_bf;
    const short* Bt = Wt + (size_t)z * NE * NE;
    short* C = qkv + (size_t)z * MM * NE;

    const int tid = threadIdx.x;
    const int lane = tid & 63, wid = tid >> 6;
    const int l15 = lane & 15, lg = lane >> 4;
    const int wr = wid >> 1, wc = wid & 1;
    const int m0 = yblk * 128, n0 = xblk * 128;

    const short* gA = A  + (size_t)(m0 + (tid >> 2)) * NE + (tid & 3) * 8;
    const short* gB = Bt + (size_t)(n0 + (tid >> 2)) * NE + (tid & 3) * 8;

    floatx4 acc[4][4];
    floatx4 zero = {0.f, 0.f, 0.f, 0.f};
    #pragma unroll
    for (int i = 0; i < 4; i++)
        #pragma unroll
        for (int j = 0; j < 4; j++) acc[i][j] = zero;

#define GSTAGE(bi, kt) do { \
    gload_lds16(gA + (kt),            &sA[bi][wid * 512]); \
    gload_lds16(gA + 64 * NE + (kt),  &sA[bi][wid * 512 + 2048]); \
    gload_lds16(gB + (kt),            &sB[bi][wid * 512]); \
    gload_lds16(gB + 64 * NE + (kt),  &sB[bi][wid * 512 + 2048]); \
} while (0)

#define GCOMP(cur) do { \
    short8 af[4], bfr[4]; \
    _Pragma("unroll") \
    for (int i = 0; i < 4; i++) { \
        af[i]  = *(const short8*)&sA[cur][(wr * 64 + i * 16 + l15) * 32 + lg * 8]; \
        bfr[i] = *(const short8*)&sB[cur][(wc * 64 + i * 16 + l15) * 32 + lg * 8]; \
    } \
    __builtin_amdgcn_s_setprio(1); \
    _Pragma("unroll") \
    for (int i = 0; i < 4; i++) \
        _Pragma("unroll") \
        for (int j = 0; j < 4; j++) \
            acc[i][j] = __builtin_amdgcn_mfma_f32_16x16x32_bf16(af[i], bfr[j], acc[i][j], 0, 0, 0); \
    __builtin_amdgcn_s_setprio(0); \
} while (0)

    GSTAGE(0, 0);
    GSTAGE(1, 32);
    for (int t = 0; t < 31; ++t) {
        asm volatile("s_waitcnt vmcnt(4)" ::: "memory");
        __builtin_amdgcn_sched_barrier(0);
        __builtin_amdgcn_s_barrier();
        __builtin_amdgcn_sched_barrier(0);
        if (t < 30) GSTAGE((t + 2) % 3, (t + 2) * 32);
        GCOMP(t % 3);
    }
    asm volatile("s_waitcnt vmcnt(0)" ::: "memory");
    __builtin_amdgcn_sched_barrier(0);
    __builtin_amdgcn_s_barrier();
    __builtin_amdgcn_sched_barrier(0);
    GCOMP(1);   // t = 31, 31 % 3 == 1
#undef GSTAGE
#undef GCOMP

    #pragma unroll
    for (int i = 0; i < 4; i++)
        #pragma unroll
        for (int j = 0; j < 4; j++)
            #pragma unroll
            for (int r = 0; r < 4; r++) {
                int row = m0 + wr * 64 + i * 16 + lg * 4 + r;
                int col = n0 + wc * 64 + j * 16 + l15;
                C[(size_t)row * NE + col] = f2bf(acc[i][j][r]);
            }
}

// ---- v [B*T, NE] bf16 -> vt[(bh)*64+d][s'] bf16, s' swizzled within 64-blocks ----
__global__ void vtrans(const short* __restrict__ v, short* __restrict__ vt) {
    __shared__ short t[64][65];
    int s0 = blockIdx.x * 64;
    int bh = blockIdx.y;
    int b = bh >> 4, h = bh & 15;
    int tid = threadIdx.x;
    int c = tid & 63, rr = tid >> 6;
    #pragma unroll
    for (int i = 0; i < 16; i++)
        t[i * 4 + rr][c] = v[(size_t)(b * TT + s0 + i * 4 + rr) * NE + h * HD + c];
    __syncthreads();
    int csw = (c & 35) | (((c >> 4) & 1) << 2) | (((c >> 2) & 3) << 3);
    #pragma unroll
    for (int i = 0; i < 16; i++)
        vt[(size_t)(bh * HD + i * 4 + rr) * TT + s0 + csw] = t[c][i * 4 + rr];
}

// ---- flash attention v12: v10 skeleton widened to 64 q-rows/wave (qb=4,
//      grid 256, 1 block/CU) — halves duplicated K/V LDS reads per q-row.
//      STAGE/KREAD/VREAD identical to v10; two paf banks (A=qb01, B=qb23);
//      sacc reused between pairs. Static-max softmax, v_exp/v_cvt_pk,
//      ones-MFMA l, cross-tile pipeline. ----
__global__ void __launch_bounds__(256, 1) fattn(const short* __restrict__ q,
                                                const short* __restrict__ k,
                                                const short* __restrict__ vt,
                                                float* __restrict__ out) {
    __shared__ short kbuf[3][4096];
    __shared__ short vbuf[3][4096];
    const int tid = threadIdx.x, lane = tid & 63, wid = tid >> 6;
    const int l15 = lane & 15, lg = lane >> 4;
    // XCD swizzle: all 8 q-blocks of one (b,h) share bid%8 -> one XCD's L2
    const int bid = blockIdx.x;                  // 0..255
    const int xcd = bid & 7, rest = bid >> 3;    // rest 0..31
    const int qblk = rest & 7;
    const int bh = xcd + 8 * (rest >> 3);
    const int b = bh >> 4, h = bh & 15;
    const int q0 = qblk * 256 + wid * 64;

    short8 qf[4][2];
    #pragma unroll
    for (int qb = 0; qb < 4; qb++) {
        const short* qp = q + (size_t)(b * TT + q0 + qb * 16 + l15) * NE + h * HD + lg * 8;
        qf[qb][0] = *(const short8*)qp;
        qf[qb][1] = *(const short8*)(qp + 32);
    }
    short8 ones;
    #pragma unroll
    for (int j = 0; j < 8; j++) ones[j] = (short)0x3F80;  // bf16 1.0

    floatx4 acc_o[4][4];
    floatx4 acc_l[4];
    floatx4 zero = {0.f, 0.f, 0.f, 0.f};
    floatx4 minus8 = {-8.f, -8.f, -8.f, -8.f};
    #pragma unroll
    for (int qb = 0; qb < 4; qb++) {
        acc_l[qb] = zero;
        #pragma unroll
        for (int db = 0; db < 4; db++) acc_o[qb][db] = zero;
    }

    const char* kgb = (const char*)(k + (size_t)(b * TT) * NE + h * HD);
    const char* vgb = (const char*)(vt + (size_t)bh * HD * TT);
    const int srow = tid >> 3;               // 0..31 (+32 via 2nd instr)
    const int ssw  = ((tid & 7) * 16) ^ ((srow & 7) << 4);
    const char* ksrc = kgb + (size_t)srow * (NE * 2) + ssw;
    const char* vsrc = vgb + (size_t)srow * (TT * 2) + ssw;

    const int swz  = (l15 & 7) << 4;
    const int rd0  = l15 * 128 + ((lg * 16) ^ swz);
    const int rd1  = l15 * 128 + ((64 + lg * 16) ^ swz);

#define STAGE(bi, s0v) do { \
    const char* ks_ = ksrc + (size_t)(s0v) * (NE * 2); \
    gload_lds16(ks_,                 &kbuf[bi][wid * 512]); \
    gload_lds16(ks_ + 32 * (NE * 2), &kbuf[bi][wid * 512 + 2048]); \
    const char* vs_ = vsrc + (size_t)(s0v) * 2; \
    gload_lds16(vs_,                 &vbuf[bi][wid * 512]); \
    gload_lds16(vs_ + 32 * (TT * 2), &vbuf[bi][wid * 512 + 2048]); \
} while (0)

#define KREAD(bi) do { \
    const char* kb_ = (const char*)kbuf[bi]; \
    _Pragma("unroll") \
    for (int cb = 0; cb < 4; cb++) { \
        kfr[cb][0] = *(const short8*)(kb_ + cb * 2048 + rd0); \
        kfr[cb][1] = *(const short8*)(kb_ + cb * 2048 + rd1); \
    } \
} while (0)

#define VREAD(bi) do { \
    const char* vb_ = (const char*)vbuf[bi]; \
    _Pragma("unroll") \
    for (int db = 0; db < 4; db++) { \
        vf[0][db] = *(const short8*)(vb_ + db * 2048 + rd0); \
        vf[1][db] = *(const short8*)(vb_ + db * 2048 + rd1); \
    } \
} while (0)

// QK for qb pair {base, base+1} -> sacc (C-init -8 bakes the static-max shift)
#define QK2(base) do { \
    _Pragma("unroll") \
    for (int q2 = 0; q2 < 2; q2++) \
        _Pragma("unroll") \
        for (int cb = 0; cb < 4; cb++) sacc[q2][cb] = minus8; \
    __builtin_amdgcn_s_setprio(1); \
    _Pragma("unroll") \
    for (int q2 = 0; q2 < 2; q2++) \
        _Pragma("unroll") \
        for (int cb = 0; cb < 4; cb++) { \
            sacc[q2][cb] = __builtin_amdgcn_mfma_f32_16x16x32_bf16(kfr[cb][0], qf[(base) + q2][0], sacc[q2][cb], 0, 0, 0); \
            sacc[q2][cb] = __builtin_amdgcn_mfma_f32_16x16x32_bf16(kfr[cb][1], qf[(base) + q2][1], sacc[q2][cb], 0, 0, 0); \
        } \
    __builtin_amdgcn_s_setprio(0); \
} while (0)

// exp + pack sacc pair -> PAF[2][2]
#define EXP2(PAF) do { \
    _Pragma("unroll") \
    for (int q2 = 0; q2 < 2; q2++) { \
        float pe[16]; \
        _Pragma("unroll") \
        for (int cb = 0; cb < 4; cb++) \
            _Pragma("unroll") \
            for (int r = 0; r < 4; r++) \
                pe[cb * 4 + r] = fast_exp2(sacc[q2][cb][r]); \
        _Pragma("unroll") \
        for (int ks = 0; ks < 2; ks++) { \
            union { uint32_t u[4]; short8 s; } pk_; \
            _Pragma("unroll") \
            for (int j2 = 0; j2 < 4; j2++) \
                asm("v_cvt_pk_bf16_f32 %0, %1, %2" \
                    : "=v"(pk_.u[j2]) \
                    : "v"(pe[ks * 8 + 2 * j2]), "v"(pe[ks * 8 + 2 * j2 + 1])); \
            PAF[q2][ks] = pk_.s; \
        } \
    } \
} while (0)

// PV for one qb using fragment PAFQ (= PAF[q2]) (8 O-MFMAs + 2 l-MFMAs)
#define PV1(qb_, PAFQ) do { \
    __builtin_amdgcn_s_setprio(1); \
    _Pragma("unroll") \
    for (int ks = 0; ks < 2; ks++) { \
        _Pragma("unroll") \
        for (int db = 0; db < 4; db++) \
            acc_o[qb_][db] = __builtin_amdgcn_mfma_f32_16x16x32_bf16(PAFQ[ks], vf[ks][db], acc_o[qb_][db], 0, 0, 0); \
        acc_l[qb_] = __builtin_amdgcn_mfma_f32_16x16x32_bf16(PAFQ[ks], ones, acc_l[qb_], 0, 0, 0); \
    } \
    __builtin_amdgcn_s_setprio(0); \
} while (0)

    short8 kfr[4][2];
    short8 vf[2][4];
    short8 pafA[2][2], pafB[2][2];
    floatx4 sacc[2][4];

    // prologue: stage tiles 0,1,2; publish; compute pafA/pafB (tile 0), vf(0)
    STAGE(0, 0);
    STAGE(1, 64);
    STAGE(2, 128);
    asm volatile("s_waitcnt vmcnt(0)" ::: "memory");
    __builtin_amdgcn_sched_barrier(0);
    __builtin_amdgcn_s_barrier();
    __builtin_amdgcn_sched_barrier(0);
    KREAD(0);
    VREAD(0);
    QK2(0);
    EXP2(pafA);
    QK2(2);
    EXP2(pafB);

    // iter t: PV(t) for 4 qb overlapped with kfr(t+1) read + QK(t+1) for both
    // pairs; EXP(t+1) overlaps MFMA drain. End-of-iter barrier publishes
    // buf[(t+2)%3]; STAGE(t+3) then overwrites buf[t%3], whose tile-t reads
    // all completed earlier this iteration.
    for (int t = 0; t < 31; ++t) {
        KREAD((t + 1) % 3);
        PV1(0, pafA[0]);
        QK2(0);            // tile t+1, pair A (waits on kfr lgkm)
        PV1(1, pafA[1]);
        EXP2(pafA);        // pafA := tile t+1 (pair A fully consumed)
        PV1(2, pafB[0]);
        QK2(2);            // tile t+1, pair B
        PV1(3, pafB[1]);
        VREAD((t + 1) % 3);  // vf(t) fully consumed above
        EXP2(pafB);        // pafB := tile t+1
        asm volatile("s_waitcnt vmcnt(0)" ::: "memory");
        __builtin_amdgcn_sched_barrier(0);
        __builtin_amdgcn_s_barrier();
        __builtin_amdgcn_sched_barrier(0);
        if (t <= 28) STAGE(t % 3, (t + 3) * 64);
    }
    // tail: PV(31) for all 4 qb
    PV1(0, pafA[0]);
    PV1(1, pafA[1]);
    PV1(2, pafB[0]);
    PV1(3, pafB[1]);
#undef STAGE
#undef KREAD
#undef VREAD
#undef QK2
#undef EXP2
#undef PV1

    // epilogue: acc_l[qb][r] = l for q-row 4lg+r (all lanes) — no shuffles
    #pragma unroll
    for (int qb = 0; qb < 4; qb++) {
        #pragma unroll
        for (int r = 0; r < 4; r++) {
            float inv = 1.0f / acc_l[qb][r];
            #pragma unroll
            for (int db = 0; db < 4; db++)
                out[(size_t)(b * TT + q0 + qb * 16 + lg * 4 + r) * NE + h * HD + db * 16 + l15] =
                    acc_o[qb][db][r] * inv;
        }
    }
}

extern "C" void kernel_launch(void* const* d_in, const int* in_sizes, int n_in,
                              void* d_out, int out_size, void* d_ws, size_t ws_size,
                              hipStream_t stream) {
    const float* x_enc = (const float*)d_in[0];
    const float* x     = (const float*)d_in[1];
    const float* Wk    = (const float*)d_in[2];
    const float* Wq    = (const float*)d_in[3];
    const float* Wv    = (const float*)d_in[4];
    float* out = (float*)d_out;

    const size_t SZ = (size_t)MM * NE;
    short* x_bf    = (short*)d_ws;
    short* xenc_bf = x_bf + SZ;
    short* Wt      = xenc_bf + SZ;
    short* qkv     = Wt + 3 * (size_t)NE * NE;
    short* vt      = qkv + 3 * SZ;

    cvt_bf16_2<<<dim3(4096), dim3(256), 0, stream>>>(x, x_enc, x_bf, xenc_bf, (int)(SZ / 8));
    wtrans<<<dim3(32, 32, 3), dim3(256), 0, stream>>>(Wq, Wk, Wv, Wt);
    gemm_bt<<<dim3(768), dim3(256), 0, stream>>>(x_bf, xenc_bf, Wt, qkv);
    vtrans<<<dim3(32, 32), dim3(256), 0, stream>>>(qkv + 2 * SZ, vt);
    fattn<<<dim3(256), dim3(256), 0, stream>>>(qkv, qkv + SZ, vt, out);
}

// Round 18
// 89.841 us; speedup vs baseline: 1.1635x; 1.1635x over previous
//
#include <hip/hip_runtime.h>
#include <hip/hip_bf16.h>
#include <stdint.h>

#define NE 1024
#define NH 16
#define HD 64
#define BB 2
#define TT 2048
#define MM (BB*TT)

typedef __attribute__((ext_vector_type(8))) short short8;
typedef __attribute__((ext_vector_type(4))) float floatx4;

__device__ __forceinline__ short f2bf(float f) {
    union { float f; uint32_t u; } v; v.f = f;
    uint32_t u = v.u;
    return (short)((u + 0x7fffu + ((u >> 16) & 1u)) >> 16);
}

__device__ __forceinline__ float fast_exp2(float x) {
#if __has_builtin(__builtin_amdgcn_exp2f)
    return __builtin_amdgcn_exp2f(x);
#else
    float r; asm("v_exp_f32 %0, %1" : "=v"(r) : "v"(x)); return r;
#endif
}

__device__ __forceinline__ void gload_lds16(const void* g, void* l) {
    __builtin_amdgcn_global_load_lds((__attribute__((address_space(1))) void*)g,
                                     (__attribute__((address_space(3))) void*)l,
                                     16, 0, 0);
}

// ---- fp32 -> bf16 for both inputs in one launch ----
__global__ void cvt_bf16_2(const float* __restrict__ ina, const float* __restrict__ inb,
                           short* __restrict__ outa, short* __restrict__ outb, int n8half) {
    int i = blockIdx.x * blockDim.x + threadIdx.x;
    const float* in; short* out; int j;
    if (i < n8half) { in = ina; out = outa; j = i; }
    else            { in = inb; out = outb; j = i - n8half; }
    const floatx4* p = (const floatx4*)(in + (size_t)j * 8);
    floatx4 a = p[0], b = p[1];
    union { uint32_t u[4]; short8 s; } r;
    asm("v_cvt_pk_bf16_f32 %0, %1, %2" : "=v"(r.u[0]) : "v"(a[0]), "v"(a[1]));
    asm("v_cvt_pk_bf16_f32 %0, %1, %2" : "=v"(r.u[1]) : "v"(a[2]), "v"(a[3]));
    asm("v_cvt_pk_bf16_f32 %0, %1, %2" : "=v"(r.u[2]) : "v"(b[0]), "v"(b[1]));
    asm("v_cvt_pk_bf16_f32 %0, %1, %2" : "=v"(r.u[3]) : "v"(b[2]), "v"(b[3]));
    *(short8*)(out + (size_t)j * 8) = r.s;
}

// ---- W [K,N] fp32 -> Wt [N,K] bf16 (transpose + convert; q pre-scaled) ----
__global__ void wtrans(const float* __restrict__ Wq, const float* __restrict__ Wk,
                       const float* __restrict__ Wv, short* __restrict__ Wt) {
    __shared__ float t[32][33];
    const float* W = blockIdx.z == 0 ? Wq : (blockIdx.z == 1 ? Wk : Wv);
    const float sc = (blockIdx.z == 0) ? 0.04508422f : 1.0f;  // (1/32)*log2(e)
    short* dst = Wt + (size_t)blockIdx.z * NE * NE;
    int n0 = blockIdx.x * 32, k0 = blockIdx.y * 32;
    int tx = threadIdx.x & 31, ty = threadIdx.x >> 5;
    #pragma unroll
    for (int i = 0; i < 4; i++)
        t[ty * 4 + i][tx] = W[(size_t)(k0 + ty * 4 + i) * NE + n0 + tx];
    __syncthreads();
    #pragma unroll
    for (int i = 0; i < 4; i++)
        dst[(size_t)(n0 + ty * 4 + i) * NE + k0 + tx] = f2bf(t[tx][ty * 4 + i] * sc);
}

// ---- GEMM (R6 structure): C[M,N] bf16 = A[M,K] @ Bt[N,K]^T ; 128x128 tile,
//      4 waves (2x2, acc 4x4), BK=32, 3-buf counted-vmcnt pipeline, XCD swizzle. ----
__global__ void __launch_bounds__(256) gemm_bt(const short* __restrict__ x_bf,
                                               const short* __restrict__ xenc_bf,
                                               const short* __restrict__ Wt,
                                               short* __restrict__ qkv) {
    __shared__ short sA[3][4096];
    __shared__ short sB[3][4096];
    const int bid = blockIdx.x;
    const int xcd = bid & 7, inner = bid >> 3;   // bid = xcd + 8*(x + 8*(yh + 4*z))
    const int xblk = inner & 7;
    const int yh = (inner >> 3) & 3;
    const int z = inner >> 5;
    const int yblk = xcd + 8 * yh;

    const short* A  = (z == 0) ? x_bf : xenc_bf;
    const short* Bt = Wt + (size_t)z * NE * NE;
    short* C = qkv + (size_t)z * MM * NE;

    const int tid = threadIdx.x;
    const int lane = tid & 63, wid = tid >> 6;
    const int l15 = lane & 15, lg = lane >> 4;
    const int wr = wid >> 1, wc = wid & 1;
    const int m0 = yblk * 128, n0 = xblk * 128;

    const short* gA = A  + (size_t)(m0 + (tid >> 2)) * NE + (tid & 3) * 8;
    const short* gB = Bt + (size_t)(n0 + (tid >> 2)) * NE + (tid & 3) * 8;

    floatx4 acc[4][4];
    floatx4 zero = {0.f, 0.f, 0.f, 0.f};
    #pragma unroll
    for (int i = 0; i < 4; i++)
        #pragma unroll
        for (int j = 0; j < 4; j++) acc[i][j] = zero;

#define GSTAGE(bi, kt) do { \
    gload_lds16(gA + (kt),            &sA[bi][wid * 512]); \
    gload_lds16(gA + 64 * NE + (kt),  &sA[bi][wid * 512 + 2048]); \
    gload_lds16(gB + (kt),            &sB[bi][wid * 512]); \
    gload_lds16(gB + 64 * NE + (kt),  &sB[bi][wid * 512 + 2048]); \
} while (0)

#define GCOMP(cur) do { \
    short8 af[4], bfr[4]; \
    _Pragma("unroll") \
    for (int i = 0; i < 4; i++) { \
        af[i]  = *(const short8*)&sA[cur][(wr * 64 + i * 16 + l15) * 32 + lg * 8]; \
        bfr[i] = *(const short8*)&sB[cur][(wc * 64 + i * 16 + l15) * 32 + lg * 8]; \
    } \
    __builtin_amdgcn_s_setprio(1); \
    _Pragma("unroll") \
    for (int i = 0; i < 4; i++) \
        _Pragma("unroll") \
        for (int j = 0; j < 4; j++) \
            acc[i][j] = __builtin_amdgcn_mfma_f32_16x16x32_bf16(af[i], bfr[j], acc[i][j], 0, 0, 0); \
    __builtin_amdgcn_s_setprio(0); \
} while (0)

    GSTAGE(0, 0);
    GSTAGE(1, 32);
    for (int t = 0; t < 31; ++t) {
        asm volatile("s_waitcnt vmcnt(4)" ::: "memory");
        __builtin_amdgcn_sched_barrier(0);
        __builtin_amdgcn_s_barrier();
        __builtin_amdgcn_sched_barrier(0);
        if (t < 30) GSTAGE((t + 2) % 3, (t + 2) * 32);
        GCOMP(t % 3);
    }
    asm volatile("s_waitcnt vmcnt(0)" ::: "memory");
    __builtin_amdgcn_sched_barrier(0);
    __builtin_amdgcn_s_barrier();
    __builtin_amdgcn_sched_barrier(0);
    GCOMP(1);   // t = 31, 31 % 3 == 1
#undef GSTAGE
#undef GCOMP

    #pragma unroll
    for (int i = 0; i < 4; i++)
        #pragma unroll
        for (int j = 0; j < 4; j++)
            #pragma unroll
            for (int r = 0; r < 4; r++) {
                int row = m0 + wr * 64 + i * 16 + lg * 4 + r;
                int col = n0 + wc * 64 + j * 16 + l15;
                C[(size_t)row * NE + col] = f2bf(acc[i][j][r]);
            }
}

// ---- v [B*T, NE] bf16 -> vt[(bh)*64+d][s'] bf16, s' swizzled within 64-blocks ----
__global__ void vtrans(const short* __restrict__ v, short* __restrict__ vt) {
    __shared__ short t[64][65];
    int s0 = blockIdx.x * 64;
    int bh = blockIdx.y;
    int b = bh >> 4, h = bh & 15;
    int tid = threadIdx.x;
    int c = tid & 63, rr = tid >> 6;
    #pragma unroll
    for (int i = 0; i < 16; i++)
        t[i * 4 + rr][c] = v[(size_t)(b * TT + s0 + i * 4 + rr) * NE + h * HD + c];
    __syncthreads();
    int csw = (c & 35) | (((c >> 4) & 1) << 2) | (((c >> 2) & 3) << 3);
    #pragma unroll
    for (int i = 0; i < 16; i++)
        vt[(size_t)(bh * HD + i * 4 + rr) * TT + s0 + csw] = t[c][i * 4 + rr];
}

// ---- flash attention v10 (known good): cross-tile software pipeline — PV(t)
//      overlapped under kfr-read latency and QK(t+1); exp/cvt(t+1) overlaps
//      MFMA drain. 32 q-rows/wave, 3-buf LDS, XCD swizzle, static-max softmax
//      in MFMA C-init, v_exp/v_cvt_pk, ones-MFMA l. ----
__global__ void __launch_bounds__(256, 2) fattn(const short* __restrict__ q,
                                                const short* __restrict__ k,
                                                const short* __restrict__ vt,
                                                float* __restrict__ out) {
    __shared__ short kbuf[3][4096];
    __shared__ short vbuf[3][4096];
    const int tid = threadIdx.x, lane = tid & 63, wid = tid >> 6;
    const int l15 = lane & 15, lg = lane >> 4;
    // XCD swizzle: all 16 q-blocks of one (b,h) share bid%8 -> one XCD's L2
    const int bid = blockIdx.x;                  // 0..511
    const int xcd = bid & 7, rest = bid >> 3;    // rest 0..63
    const int qblk = rest & 15;
    const int bh = xcd + 8 * (rest >> 4);
    const int b = bh >> 4, h = bh & 15;
    const int q0 = qblk * 128 + wid * 32;

    short8 qf[2][2];
    #pragma unroll
    for (int qb = 0; qb < 2; qb++) {
        const short* qp = q + (size_t)(b * TT + q0 + qb * 16 + l15) * NE + h * HD + lg * 8;
        qf[qb][0] = *(const short8*)qp;
        qf[qb][1] = *(const short8*)(qp + 32);
    }
    short8 ones;
    #pragma unroll
    for (int j = 0; j < 8; j++) ones[j] = (short)0x3F80;  // bf16 1.0

    floatx4 acc_o[2][4];
    floatx4 acc_l[2];
    floatx4 zero = {0.f, 0.f, 0.f, 0.f};
    floatx4 minus8 = {-8.f, -8.f, -8.f, -8.f};
    #pragma unroll
    for (int qb = 0; qb < 2; qb++) {
        acc_l[qb] = zero;
        #pragma unroll
        for (int db = 0; db < 4; db++) acc_o[qb][db] = zero;
    }

    const char* kgb = (const char*)(k + (size_t)(b * TT) * NE + h * HD);
    const char* vgb = (const char*)(vt + (size_t)bh * HD * TT);
    const int srow = tid >> 3;               // 0..31 (+32 via 2nd instr)
    const int ssw  = ((tid & 7) * 16) ^ ((srow & 7) << 4);
    const char* ksrc = kgb + (size_t)srow * (NE * 2) + ssw;
    const char* vsrc = vgb + (size_t)srow * (TT * 2) + ssw;

    const int swz  = (l15 & 7) << 4;
    const int rd0  = l15 * 128 + ((lg * 16) ^ swz);
    const int rd1  = l15 * 128 + ((64 + lg * 16) ^ swz);

#define STAGE(bi, s0v) do { \
    const char* ks_ = ksrc + (size_t)(s0v) * (NE * 2); \
    gload_lds16(ks_,                 &kbuf[bi][wid * 512]); \
    gload_lds16(ks_ + 32 * (NE * 2), &kbuf[bi][wid * 512 + 2048]); \
    const char* vs_ = vsrc + (size_t)(s0v) * 2; \
    gload_lds16(vs_,                 &vbuf[bi][wid * 512]); \
    gload_lds16(vs_ + 32 * (TT * 2), &vbuf[bi][wid * 512 + 2048]); \
} while (0)

#define KREAD(bi) do { \
    const char* kb_ = (const char*)kbuf[bi]; \
    _Pragma("unroll") \
    for (int cb = 0; cb < 4; cb++) { \
        kfr[cb][0] = *(const short8*)(kb_ + cb * 2048 + rd0); \
        kfr[cb][1] = *(const short8*)(kb_ + cb * 2048 + rd1); \
    } \
} while (0)

#define VREAD(bi) do { \
    const char* vb_ = (const char*)vbuf[bi]; \
    _Pragma("unroll") \
    for (int db = 0; db < 4; db++) { \
        vf[0][db] = *(const short8*)(vb_ + db * 2048 + rd0); \
        vf[1][db] = *(const short8*)(vb_ + db * 2048 + rd1); \
    } \
} while (0)

// QK for both qb -> sacc (C-init -8 bakes the static-max shift)
#define QK() do { \
    _Pragma("unroll") \
    for (int qb = 0; qb < 2; qb++) \
        _Pragma("unroll") \
        for (int cb = 0; cb < 4; cb++) sacc[qb][cb] = minus8; \
    __builtin_amdgcn_s_setprio(1); \
    _Pragma("unroll") \
    for (int qb = 0; qb < 2; qb++) \
        _Pragma("unroll") \
        for (int cb = 0; cb < 4; cb++) { \
            sacc[qb][cb] = __builtin_amdgcn_mfma_f32_16x16x32_bf16(kfr[cb][0], qf[qb][0], sacc[qb][cb], 0, 0, 0); \
            sacc[qb][cb] = __builtin_amdgcn_mfma_f32_16x16x32_bf16(kfr[cb][1], qf[qb][1], sacc[qb][cb], 0, 0, 0); \
        } \
    __builtin_amdgcn_s_setprio(0); \
} while (0)

// exp + pack both qb -> paf
#define EXPCVT() do { \
    _Pragma("unroll") \
    for (int qb = 0; qb < 2; qb++) { \
        float pe[16]; \
        _Pragma("unroll") \
        for (int cb = 0; cb < 4; cb++) \
            _Pragma("unroll") \
            for (int r = 0; r < 4; r++) \
                pe[cb * 4 + r] = fast_exp2(sacc[qb][cb][r]); \
        _Pragma("unroll") \
        for (int ks = 0; ks < 2; ks++) { \
            union { uint32_t u[4]; short8 s; } pk_; \
            _Pragma("unroll") \
            for (int j2 = 0; j2 < 4; j2++) \
                asm("v_cvt_pk_bf16_f32 %0, %1, %2" \
                    : "=v"(pk_.u[j2]) \
                    : "v"(pe[ks * 8 + 2 * j2]), "v"(pe[ks * 8 + 2 * j2 + 1])); \
            paf[qb][ks] = pk_.s; \
        } \
    } \
} while (0)

// PV for one qb (8 O-MFMAs + 2 l-MFMAs)
#define PVH(qb) do { \
    __builtin_amdgcn_s_setprio(1); \
    _Pragma("unroll") \
    for (int ks = 0; ks < 2; ks++) { \
        _Pragma("unroll") \
        for (int db = 0; db < 4; db++) \
            acc_o[qb][db] = __builtin_amdgcn_mfma_f32_16x16x32_bf16(paf[qb][ks], vf[ks][db], acc_o[qb][db], 0, 0, 0); \
        acc_l[qb] = __builtin_amdgcn_mfma_f32_16x16x32_bf16(paf[qb][ks], ones, acc_l[qb], 0, 0, 0); \
    } \
    __builtin_amdgcn_s_setprio(0); \
} while (0)

    short8 kfr[4][2];
    short8 vf[2][4];
    short8 paf[2][2];
    floatx4 sacc[2][4];

    // prologue: stage tiles 0,1,2; publish; compute paf(0)/vf(0)
    STAGE(0, 0);
    STAGE(1, 64);
    STAGE(2, 128);
    asm volatile("s_waitcnt vmcnt(0)" ::: "memory");
    __builtin_amdgcn_sched_barrier(0);
    __builtin_amdgcn_s_barrier();
    __builtin_amdgcn_sched_barrier(0);
    KREAD(0);
    VREAD(0);
    QK();
    EXPCVT();

    // iter t: PV(t) overlapped with kfr(t+1) read + QK(t+1); exp/cvt(t+1)
    // overlaps MFMA drain. End-of-iter barrier publishes buf[(t+2)%3]
    // (STAGE(t+2) issued at end of iter t-1 / prologue); STAGE(t+3) then
    // overwrites buf[t%3], whose tile-t reads completed in iter t-1.
    for (int t = 0; t < 31; ++t) {
        KREAD((t + 1) % 3);
        PVH(0);
        QK();            // tile t+1 (compiler inserts lgkm wait on kfr)
        PVH(1);
        VREAD((t + 1) % 3);
        EXPCVT();        // tile t+1 -> paf; overlaps queued MFMA drain
        asm volatile("s_waitcnt vmcnt(0)" ::: "memory");
        __builtin_amdgcn_sched_barrier(0);
        __builtin_amdgcn_s_barrier();
        __builtin_amdgcn_sched_barrier(0);
        if (t <= 28) STAGE(t % 3, (t + 3) * 64);
    }
    // tail: PV(31)
    PVH(0);
    PVH(1);
#undef STAGE
#undef KREAD
#undef VREAD
#undef QK
#undef EXPCVT
#undef PVH

    // epilogue: acc_l[qb][r] = l for q-row 4lg+r (all lanes) — no shuffles
    #pragma unroll
    for (int qb = 0; qb < 2; qb++) {
        #pragma unroll
        for (int r = 0; r < 4; r++) {
            float inv = 1.0f / acc_l[qb][r];
            #pragma unroll
            for (int db = 0; db < 4; db++)
                out[(size_t)(b * TT + q0 + qb * 16 + lg * 4 + r) * NE + h * HD + db * 16 + l15] =
                    acc_o[qb][db][r] * inv;
        }
    }
}

extern "C" void kernel_launch(void* const* d_in, const int* in_sizes, int n_in,
                              void* d_out, int out_size, void* d_ws, size_t ws_size,
                              hipStream_t stream) {
    const float* x_enc = (const float*)d_in[0];
    const float* x     = (const float*)d_in[1];
    const float* Wk    = (const float*)d_in[2];
    const float* Wq    = (const float*)d_in[3];
    const float* Wv    = (const float*)d_in[4];
    float* out = (float*)d_out;

    const size_t SZ = (size_t)MM * NE;
    short* x_bf    = (short*)d_ws;
    short* xenc_bf = x_bf + SZ;
    short* Wt      = xenc_bf + SZ;
    short* qkv     = Wt + 3 * (size_t)NE * NE;
    short* vt      = qkv + 3 * SZ;

    cvt_bf16_2<<<dim3(4096), dim3(256), 0, stream>>>(x, x_enc, x_bf, xenc_bf, (int)(SZ / 8));
    wtrans<<<dim3(32, 32, 3), dim3(256), 0, stream>>>(Wq, Wk, Wv, Wt);
    gemm_bt<<<dim3(768), dim3(256), 0, stream>>>(x_bf, xenc_bf, Wt, qkv);
    vtrans<<<dim3(32, 32), dim3(256), 0, stream>>>(qkv + 2 * SZ, vt);
    fattn<<<dim3(512), dim3(256), 0, stream>>>(qkv, qkv + SZ, vt, out);
}

// Round 19
// 87.457 us; speedup vs baseline: 1.1953x; 1.0273x over previous
//
#include <hip/hip_runtime.h>
#include <hip/hip_bf16.h>
#include <stdint.h>

#define NE 1024
#define NH 16
#define HD 64
#define BB 2
#define TT 2048
#define MM (BB*TT)

typedef __attribute__((ext_vector_type(8))) short short8;
typedef __attribute__((ext_vector_type(4))) float floatx4;

__device__ __forceinline__ short f2bf(float f) {
    union { float f; uint32_t u; } v; v.f = f;
    uint32_t u = v.u;
    return (short)((u + 0x7fffu + ((u >> 16) & 1u)) >> 16);
}

__device__ __forceinline__ float fast_exp2(float x) {
#if __has_builtin(__builtin_amdgcn_exp2f)
    return __builtin_amdgcn_exp2f(x);
#else
    float r; asm("v_exp_f32 %0, %1" : "=v"(r) : "v"(x)); return r;
#endif
}

__device__ __forceinline__ void gload_lds16(const void* g, void* l) {
    __builtin_amdgcn_global_load_lds((__attribute__((address_space(1))) void*)g,
                                     (__attribute__((address_space(3))) void*)l,
                                     16, 0, 0);
}

// ---- fused: fp32->bf16 cvt for x,x_enc (blocks 0..4095) + W transpose/convert
//      (blocks 4096..7167). Single change vs R18 baseline (fattn untouched). ----
__global__ void cvt_wtrans(const float* __restrict__ x, const float* __restrict__ x_enc,
                           short* __restrict__ x_bf, short* __restrict__ xenc_bf,
                           const float* __restrict__ Wq, const float* __restrict__ Wk,
                           const float* __restrict__ Wv, short* __restrict__ Wt,
                           int n8half) {
    __shared__ float t[32][33];
    const int bx = blockIdx.x;
    if (bx < 4096) {
        int i = bx * blockDim.x + threadIdx.x;
        const float* in; short* out; int j;
        if (i < n8half) { in = x; out = x_bf; j = i; }
        else            { in = x_enc; out = xenc_bf; j = i - n8half; }
        const floatx4* p = (const floatx4*)(in + (size_t)j * 8);
        floatx4 a = p[0], b = p[1];
        union { uint32_t u[4]; short8 s; } r;
        asm("v_cvt_pk_bf16_f32 %0, %1, %2" : "=v"(r.u[0]) : "v"(a[0]), "v"(a[1]));
        asm("v_cvt_pk_bf16_f32 %0, %1, %2" : "=v"(r.u[1]) : "v"(a[2]), "v"(a[3]));
        asm("v_cvt_pk_bf16_f32 %0, %1, %2" : "=v"(r.u[2]) : "v"(b[0]), "v"(b[1]));
        asm("v_cvt_pk_bf16_f32 %0, %1, %2" : "=v"(r.u[3]) : "v"(b[2]), "v"(b[3]));
        *(short8*)(out + (size_t)j * 8) = r.s;
    } else {
        int bb = bx - 4096;                 // 0..3071
        int z = bb >> 10;                   // 0..2
        int rem = bb & 1023;
        int n0 = (rem & 31) * 32, k0 = (rem >> 5) * 32;
        const float* W = z == 0 ? Wq : (z == 1 ? Wk : Wv);
        const float sc = (z == 0) ? 0.04508422f : 1.0f;  // (1/32)*log2(e)
        short* dst = Wt + (size_t)z * NE * NE;
        int tx = threadIdx.x & 31, ty = threadIdx.x >> 5;
        #pragma unroll
        for (int i = 0; i < 4; i++)
            t[ty * 4 + i][tx] = W[(size_t)(k0 + ty * 4 + i) * NE + n0 + tx];
        __syncthreads();
        #pragma unroll
        for (int i = 0; i < 4; i++)
            dst[(size_t)(n0 + ty * 4 + i) * NE + k0 + tx] = f2bf(t[tx][ty * 4 + i] * sc);
    }
}

// ---- GEMM (R6 structure): C[M,N] bf16 = A[M,K] @ Bt[N,K]^T ; 128x128 tile,
//      4 waves (2x2, acc 4x4), BK=32, 3-buf counted-vmcnt pipeline, XCD swizzle. ----
__global__ void __launch_bounds__(256) gemm_bt(const short* __restrict__ x_bf,
                                               const short* __restrict__ xenc_bf,
                                               const short* __restrict__ Wt,
                                               short* __restrict__ qkv) {
    __shared__ short sA[3][4096];
    __shared__ short sB[3][4096];
    const int bid = blockIdx.x;
    const int xcd = bid & 7, inner = bid >> 3;   // bid = xcd + 8*(x + 8*(yh + 4*z))
    const int xblk = inner & 7;
    const int yh = (inner >> 3) & 3;
    const int z = inner >> 5;
    const int yblk = xcd + 8 * yh;

    const short* A  = (z == 0) ? x_bf : xenc_bf;
    const short* Bt = Wt + (size_t)z * NE * NE;
    short* C = qkv + (size_t)z * MM * NE;

    const int tid = threadIdx.x;
    const int lane = tid & 63, wid = tid >> 6;
    const int l15 = lane & 15, lg = lane >> 4;
    const int wr = wid >> 1, wc = wid & 1;
    const int m0 = yblk * 128, n0 = xblk * 128;

    const short* gA = A  + (size_t)(m0 + (tid >> 2)) * NE + (tid & 3) * 8;
    const short* gB = Bt + (size_t)(n0 + (tid >> 2)) * NE + (tid & 3) * 8;

    floatx4 acc[4][4];
    floatx4 zero = {0.f, 0.f, 0.f, 0.f};
    #pragma unroll
    for (int i = 0; i < 4; i++)
        #pragma unroll
        for (int j = 0; j < 4; j++) acc[i][j] = zero;

#define GSTAGE(bi, kt) do { \
    gload_lds16(gA + (kt),            &sA[bi][wid * 512]); \
    gload_lds16(gA + 64 * NE + (kt),  &sA[bi][wid * 512 + 2048]); \
    gload_lds16(gB + (kt),            &sB[bi][wid * 512]); \
    gload_lds16(gB + 64 * NE + (kt),  &sB[bi][wid * 512 + 2048]); \
} while (0)

#define GCOMP(cur) do { \
    short8 af[4], bfr[4]; \
    _Pragma("unroll") \
    for (int i = 0; i < 4; i++) { \
        af[i]  = *(const short8*)&sA[cur][(wr * 64 + i * 16 + l15) * 32 + lg * 8]; \
        bfr[i] = *(const short8*)&sB[cur][(wc * 64 + i * 16 + l15) * 32 + lg * 8]; \
    } \
    __builtin_amdgcn_s_setprio(1); \
    _Pragma("unroll") \
    for (int i = 0; i < 4; i++) \
        _Pragma("unroll") \
        for (int j = 0; j < 4; j++) \
            acc[i][j] = __builtin_amdgcn_mfma_f32_16x16x32_bf16(af[i], bfr[j], acc[i][j], 0, 0, 0); \
    __builtin_amdgcn_s_setprio(0); \
} while (0)

    GSTAGE(0, 0);
    GSTAGE(1, 32);
    for (int t = 0; t < 31; ++t) {
        asm volatile("s_waitcnt vmcnt(4)" ::: "memory");
        __builtin_amdgcn_sched_barrier(0);
        __builtin_amdgcn_s_barrier();
        __builtin_amdgcn_sched_barrier(0);
        if (t < 30) GSTAGE((t + 2) % 3, (t + 2) * 32);
        GCOMP(t % 3);
    }
    asm volatile("s_waitcnt vmcnt(0)" ::: "memory");
    __builtin_amdgcn_sched_barrier(0);
    __builtin_amdgcn_s_barrier();
    __builtin_amdgcn_sched_barrier(0);
    GCOMP(1);   // t = 31, 31 % 3 == 1
#undef GSTAGE
#undef GCOMP

    #pragma unroll
    for (int i = 0; i < 4; i++)
        #pragma unroll
        for (int j = 0; j < 4; j++)
            #pragma unroll
            for (int r = 0; r < 4; r++) {
                int row = m0 + wr * 64 + i * 16 + lg * 4 + r;
                int col = n0 + wc * 64 + j * 16 + l15;
                C[(size_t)row * NE + col] = f2bf(acc[i][j][r]);
            }
}

// ---- v [B*T, NE] bf16 -> vt[(bh)*64+d][s'] bf16, s' swizzled within 64-blocks ----
__global__ void vtrans(const short* __restrict__ v, short* __restrict__ vt) {
    __shared__ short t[64][65];
    int s0 = blockIdx.x * 64;
    int bh = blockIdx.y;
    int b = bh >> 4, h = bh & 15;
    int tid = threadIdx.x;
    int c = tid & 63, rr = tid >> 6;
    #pragma unroll
    for (int i = 0; i < 16; i++)
        t[i * 4 + rr][c] = v[(size_t)(b * TT + s0 + i * 4 + rr) * NE + h * HD + c];
    __syncthreads();
    int csw = (c & 35) | (((c >> 4) & 1) << 2) | (((c >> 2) & 3) << 3);
    #pragma unroll
    for (int i = 0; i < 16; i++)
        vt[(size_t)(bh * HD + i * 4 + rr) * TT + s0 + csw] = t[c][i * 4 + rr];
}

// ---- flash attention v10 (known good, byte-identical to R18): cross-tile
//      software pipeline — PV(t) overlapped under kfr-read latency and
//      QK(t+1); exp/cvt(t+1) overlaps MFMA drain. 32 q-rows/wave, 3-buf LDS,
//      XCD swizzle, static-max softmax in MFMA C-init, ones-MFMA l. ----
__global__ void __launch_bounds__(256, 2) fattn(const short* __restrict__ q,
                                                const short* __restrict__ k,
                                                const short* __restrict__ vt,
                                                float* __restrict__ out) {
    __shared__ short kbuf[3][4096];
    __shared__ short vbuf[3][4096];
    const int tid = threadIdx.x, lane = tid & 63, wid = tid >> 6;
    const int l15 = lane & 15, lg = lane >> 4;
    // XCD swizzle: all 16 q-blocks of one (b,h) share bid%8 -> one XCD's L2
    const int bid = blockIdx.x;                  // 0..511
    const int xcd = bid & 7, rest = bid >> 3;    // rest 0..63
    const int qblk = rest & 15;
    const int bh = xcd + 8 * (rest >> 4);
    const int b = bh >> 4, h = bh & 15;
    const int q0 = qblk * 128 + wid * 32;

    short8 qf[2][2];
    #pragma unroll
    for (int qb = 0; qb < 2; qb++) {
        const short* qp = q + (size_t)(b * TT + q0 + qb * 16 + l15) * NE + h * HD + lg * 8;
        qf[qb][0] = *(const short8*)qp;
        qf[qb][1] = *(const short8*)(qp + 32);
    }
    short8 ones;
    #pragma unroll
    for (int j = 0; j < 8; j++) ones[j] = (short)0x3F80;  // bf16 1.0

    floatx4 acc_o[2][4];
    floatx4 acc_l[2];
    floatx4 zero = {0.f, 0.f, 0.f, 0.f};
    floatx4 minus8 = {-8.f, -8.f, -8.f, -8.f};
    #pragma unroll
    for (int qb = 0; qb < 2; qb++) {
        acc_l[qb] = zero;
        #pragma unroll
        for (int db = 0; db < 4; db++) acc_o[qb][db] = zero;
    }

    const char* kgb = (const char*)(k + (size_t)(b * TT) * NE + h * HD);
    const char* vgb = (const char*)(vt + (size_t)bh * HD * TT);
    const int srow = tid >> 3;               // 0..31 (+32 via 2nd instr)
    const int ssw  = ((tid & 7) * 16) ^ ((srow & 7) << 4);
    const char* ksrc = kgb + (size_t)srow * (NE * 2) + ssw;
    const char* vsrc = vgb + (size_t)srow * (TT * 2) + ssw;

    const int swz  = (l15 & 7) << 4;
    const int rd0  = l15 * 128 + ((lg * 16) ^ swz);
    const int rd1  = l15 * 128 + ((64 + lg * 16) ^ swz);

#define STAGE(bi, s0v) do { \
    const char* ks_ = ksrc + (size_t)(s0v) * (NE * 2); \
    gload_lds16(ks_,                 &kbuf[bi][wid * 512]); \
    gload_lds16(ks_ + 32 * (NE * 2), &kbuf[bi][wid * 512 + 2048]); \
    const char* vs_ = vsrc + (size_t)(s0v) * 2; \
    gload_lds16(vs_,                 &vbuf[bi][wid * 512]); \
    gload_lds16(vs_ + 32 * (TT * 2), &vbuf[bi][wid * 512 + 2048]); \
} while (0)

#define KREAD(bi) do { \
    const char* kb_ = (const char*)kbuf[bi]; \
    _Pragma("unroll") \
    for (int cb = 0; cb < 4; cb++) { \
        kfr[cb][0] = *(const short8*)(kb_ + cb * 2048 + rd0); \
        kfr[cb][1] = *(const short8*)(kb_ + cb * 2048 + rd1); \
    } \
} while (0)

#define VREAD(bi) do { \
    const char* vb_ = (const char*)vbuf[bi]; \
    _Pragma("unroll") \
    for (int db = 0; db < 4; db++) { \
        vf[0][db] = *(const short8*)(vb_ + db * 2048 + rd0); \
        vf[1][db] = *(const short8*)(vb_ + db * 2048 + rd1); \
    } \
} while (0)

// QK for both qb -> sacc (C-init -8 bakes the static-max shift)
#define QK() do { \
    _Pragma("unroll") \
    for (int qb = 0; qb < 2; qb++) \
        _Pragma("unroll") \
        for (int cb = 0; cb < 4; cb++) sacc[qb][cb] = minus8; \
    __builtin_amdgcn_s_setprio(1); \
    _Pragma("unroll") \
    for (int qb = 0; qb < 2; qb++) \
        _Pragma("unroll") \
        for (int cb = 0; cb < 4; cb++) { \
            sacc[qb][cb] = __builtin_amdgcn_mfma_f32_16x16x32_bf16(kfr[cb][0], qf[qb][0], sacc[qb][cb], 0, 0, 0); \
            sacc[qb][cb] = __builtin_amdgcn_mfma_f32_16x16x32_bf16(kfr[cb][1], qf[qb][1], sacc[qb][cb], 0, 0, 0); \
        } \
    __builtin_amdgcn_s_setprio(0); \
} while (0)

// exp + pack both qb -> paf
#define EXPCVT() do { \
    _Pragma("unroll") \
    for (int qb = 0; qb < 2; qb++) { \
        float pe[16]; \
        _Pragma("unroll") \
        for (int cb = 0; cb < 4; cb++) \
            _Pragma("unroll") \
            for (int r = 0; r < 4; r++) \
                pe[cb * 4 + r] = fast_exp2(sacc[qb][cb][r]); \
        _Pragma("unroll") \
        for (int ks = 0; ks < 2; ks++) { \
            union { uint32_t u[4]; short8 s; } pk_; \
            _Pragma("unroll") \
            for (int j2 = 0; j2 < 4; j2++) \
                asm("v_cvt_pk_bf16_f32 %0, %1, %2" \
                    : "=v"(pk_.u[j2]) \
                    : "v"(pe[ks * 8 + 2 * j2]), "v"(pe[ks * 8 + 2 * j2 + 1])); \
            paf[qb][ks] = pk_.s; \
        } \
    } \
} while (0)

// PV for one qb (8 O-MFMAs + 2 l-MFMAs)
#define PVH(qb) do { \
    __builtin_amdgcn_s_setprio(1); \
    _Pragma("unroll") \
    for (int ks = 0; ks < 2; ks++) { \
        _Pragma("unroll") \
        for (int db = 0; db < 4; db++) \
            acc_o[qb][db] = __builtin_amdgcn_mfma_f32_16x16x32_bf16(paf[qb][ks], vf[ks][db], acc_o[qb][db], 0, 0, 0); \
        acc_l[qb] = __builtin_amdgcn_mfma_f32_16x16x32_bf16(paf[qb][ks], ones, acc_l[qb], 0, 0, 0); \
    } \
    __builtin_amdgcn_s_setprio(0); \
} while (0)

    short8 kfr[4][2];
    short8 vf[2][4];
    short8 paf[2][2];
    floatx4 sacc[2][4];

    // prologue: stage tiles 0,1,2; publish; compute paf(0)/vf(0)
    STAGE(0, 0);
    STAGE(1, 64);
    STAGE(2, 128);
    asm volatile("s_waitcnt vmcnt(0)" ::: "memory");
    __builtin_amdgcn_sched_barrier(0);
    __builtin_amdgcn_s_barrier();
    __builtin_amdgcn_sched_barrier(0);
    KREAD(0);
    VREAD(0);
    QK();
    EXPCVT();

    // iter t: PV(t) overlapped with kfr(t+1) read + QK(t+1); exp/cvt(t+1)
    // overlaps MFMA drain. End-of-iter barrier publishes buf[(t+2)%3]
    // (STAGE(t+2) issued at end of iter t-1 / prologue); STAGE(t+3) then
    // overwrites buf[t%3], whose tile-t reads completed in iter t-1.
    for (int t = 0; t < 31; ++t) {
        KREAD((t + 1) % 3);
        PVH(0);
        QK();            // tile t+1 (compiler inserts lgkm wait on kfr)
        PVH(1);
        VREAD((t + 1) % 3);
        EXPCVT();        // tile t+1 -> paf; overlaps queued MFMA drain
        asm volatile("s_waitcnt vmcnt(0)" ::: "memory");
        __builtin_amdgcn_sched_barrier(0);
        __builtin_amdgcn_s_barrier();
        __builtin_amdgcn_sched_barrier(0);
        if (t <= 28) STAGE(t % 3, (t + 3) * 64);
    }
    // tail: PV(31)
    PVH(0);
    PVH(1);
#undef STAGE
#undef KREAD
#undef VREAD
#undef QK
#undef EXPCVT
#undef PVH

    // epilogue: acc_l[qb][r] = l for q-row 4lg+r (all lanes) — no shuffles
    #pragma unroll
    for (int qb = 0; qb < 2; qb++) {
        #pragma unroll
        for (int r = 0; r < 4; r++) {
            float inv = 1.0f / acc_l[qb][r];
            #pragma unroll
            for (int db = 0; db < 4; db++)
                out[(size_t)(b * TT + q0 + qb * 16 + lg * 4 + r) * NE + h * HD + db * 16 + l15] =
                    acc_o[qb][db][r] * inv;
        }
    }
}

extern "C" void kernel_launch(void* const* d_in, const int* in_sizes, int n_in,
                              void* d_out, int out_size, void* d_ws, size_t ws_size,
                              hipStream_t stream) {
    const float* x_enc = (const float*)d_in[0];
    const float* x     = (const float*)d_in[1];
    const float* Wk    = (const float*)d_in[2];
    const float* Wq    = (const float*)d_in[3];
    const float* Wv    = (const float*)d_in[4];
    float* out = (float*)d_out;

    const size_t SZ = (size_t)MM * NE;
    short* x_bf    = (short*)d_ws;
    short* xenc_bf = x_bf + SZ;
    short* Wt      = xenc_bf + SZ;
    short* qkv     = Wt + 3 * (size_t)NE * NE;
    short* vt      = qkv + 3 * SZ;

    cvt_wtrans<<<dim3(7168), dim3(256), 0, stream>>>(x, x_enc, x_bf, xenc_bf,
                                                     Wq, Wk, Wv, Wt, (int)(SZ / 8));
    gemm_bt<<<dim3(768), dim3(256), 0, stream>>>(x_bf, xenc_bf, Wt, qkv);
    vtrans<<<dim3(32, 32), dim3(256), 0, stream>>>(qkv + 2 * SZ, vt);
    fattn<<<dim3(512), dim3(256), 0, stream>>>(qkv, qkv + SZ, vt, out);
}